// Round 3
// baseline (302.480 us; speedup 1.0000x reference)
//
#include <hip/hip_runtime.h>

// GMMNet: B=4,S=8,C=3,H=W=384,K=5. Pointwise per pixel; scan over S carries
// per-pixel state (pi[5], mu[15], rinv[5]=1/sigma) in registers.
//
// Round 11: ONE PIXEL PER THREAD (scalar float), replacing the 2-px v2f
// scheme. R10 proved __launch_bounds__ min-waves is BEST-EFFORT: with v2f
// the carried state alone is 62 VGPRs (31 pairs) and peak ~150-200, so the
// allocator ignored the 128-reg target (VGPR_Count unchanged, occupancy
// stuck at ~30% = 2 waves/SIMD, VALUBusy 57-65% = exposed s_load latency).
// Scalar 1-px/thread: carried state 31 floats, peak ~70 regs -> 4-6
// waves/SIMD cap, and the grid now supplies 9 waves/SIMD (589,824 threads).
// Measured VALU-busy time (~87us) matches the SCALARIZED instruction-count
// estimate, not the packed one -> total VALU work should stay ~constant;
// we're spreading it over 3x the resident waves to hide latency.
// Predict: occupancy 31->55-75%, VALUBusy->~90%, dispatch 148->~95us.
// Tripwire: dur>=160us means v2f WAS packing (work doubled) -> revert and
// do explicit inline-asm v_pk_fma_f32 instead.
//
// Retained from R8: ONE contiguous d_ws weight buffer (tiny staging kernel),
// consumption-order layout, dense s_load clustering off a single base.
// Opaque scalar per-step offset retained (blocks loop-invariant weight
// hoisting into VGPRs - R2's 188-VGPR lesson).

namespace {

constexpr int Kk = 5;
constexpr int Cc = 3;
constexpr int CKc = 15;   // C*K
constexpr int Bb = 4;
constexpr int Ss = 8;
constexpr int HWc = 384 * 384;
constexpr int BLOCK = 256;

// Contiguous weight layout (float offsets), consumption order.
constexpr int OPB1 = 0;     // pi_b1   5
constexpr int OPW1 = 5;     // pi_w1   5x10 = 50
constexpr int OPB2 = 55;    // pi_b2   5
constexpr int OPW2 = 60;    // pi_w2   5x5  = 25
constexpr int OMB1 = 85;    // mu_b1   15
constexpr int OMW1 = 100;   // mu_w1   15x23 = 345
constexpr int OMB2 = 445;   // mu_b2   15
constexpr int OMW2 = 460;   // mu_w2   15x15 = 225
constexpr int OSB1 = 685;   // sg_b1   5
constexpr int OSW1 = 690;   // sg_w1   5x23 = 115
constexpr int OSB2 = 805;   // sg_b2   5
constexpr int OSW2 = 810;   // sg_w2   5x5  = 25
constexpr int OGB1 = 835;   // ga_b1   5
constexpr int OGW1 = 840;   // ga_w1   5x5  = 25
constexpr int OGW2 = 865;   // ga_w2   5
constexpr int OGB2 = 870;   // ga_b2   1
constexpr int WTOT = 871;   // 3484 B

__device__ __forceinline__ float rcpf(float x) { return __builtin_amdgcn_rcpf(x); }
__device__ __forceinline__ float ex2(float x) { return __builtin_amdgcn_exp2f(x); }
__device__ __forceinline__ float frelu(float a) { return fmaxf(a, 0.0f); }
constexpr float LOG2E = 1.4426950408889634f;
__device__ __forceinline__ float fsigm(float a) { return rcpf(1.0f + ex2(-LOG2E * a)); }

__global__ __launch_bounds__(256) void stage_ws_kernel(
    const float* __restrict__ pw1, const float* __restrict__ pb1,
    const float* __restrict__ pw2, const float* __restrict__ pb2,
    const float* __restrict__ mw1, const float* __restrict__ mb1,
    const float* __restrict__ mw2, const float* __restrict__ mb2,
    const float* __restrict__ sw1, const float* __restrict__ sb1,
    const float* __restrict__ sw2, const float* __restrict__ sb2,
    const float* __restrict__ gw1, const float* __restrict__ gb1,
    const float* __restrict__ gw2, const float* __restrict__ gb2,
    float* __restrict__ ws)
{
    const int t = threadIdx.x;
    auto cp = [&](const float* src, int off, int n) {
        for (int i = t; i < n; i += 256) ws[off + i] = src[i];
    };
    cp(pb1, OPB1, 5);   cp(pw1, OPW1, 50);
    cp(pb2, OPB2, 5);   cp(pw2, OPW2, 25);
    cp(mb1, OMB1, 15);  cp(mw1, OMW1, 345);
    cp(mb2, OMB2, 15);  cp(mw2, OMW2, 225);
    cp(sb1, OSB1, 5);   cp(sw1, OSW1, 115);
    cp(sb2, OSB2, 5);   cp(sw2, OSW2, 25);
    cp(gb1, OGB1, 5);   cp(gw1, OGW1, 25);
    cp(gw2, OGW2, 5);   cp(gb2, OGB2, 1);
}

__global__ __launch_bounds__(BLOCK, 4) void gmm_seq_kernel(
    const float* __restrict__ frames,
    const float* __restrict__ mu0,
    const float* __restrict__ Wt,     // contiguous weights in d_ws
    float* __restrict__ out)
{
    const int t = blockIdx.x * BLOCK + threadIdx.x;    // one thread = 1 pixel
    const int b   = t / HWc;
    const int rem = t - b * HWc;

    const float C0 = 0.06349363593424097f;      // (2*pi)^{-3/2}
    const float NH_L2E = -0.7213475204444817f;  // -0.5 * log2(e)

    // Per-pixel carried state (31 floats).
    float pi[Kk], mu[CKc], rinv[Kk];            // rinv = 1/sigma
#pragma unroll
    for (int k = 0; k < Kk; k++) { pi[k] = 0.2f; rinv[k] = 1.0f; }
    {
        const float* mp = mu0 + (size_t)b * CKc * HWc;
#pragma unroll
        for (int j = 0; j < CKc; j++)
            mu[j] = mp[(size_t)j * HWc + rem];
    }

    const float* fbase = frames + ((size_t)b * Ss * Cc) * HWc;
    float x[Cc];
#pragma unroll
    for (int c = 0; c < Cc; c++)
        x[c] = fbase[(size_t)c * HWc + rem];

#pragma unroll 1
    for (int s = 0; s < Ss; s++) {
        // Opaque per-iteration SCALAR offset: value is always 0 but unprovable.
        // Addresses stay wave-uniform (s_load path), loads stay loop-variant
        // (no cross-step hoisting of weight VALUES into registers).
        long woff = 0;
        asm volatile("" : "+s"(woff));
        const float* W = Wt + woff;

        // Prefetch next frame's pixels (clamped index -> branchless).
        const int sn = (s + 1 < Ss) ? s + 1 : s;
        float xn[Cc];
        {
            const float* fp = fbase + ((size_t)sn * Cc) * HWc;
#pragma unroll
            for (int c = 0; c < Cc; c++)
                xn[c] = fp[(size_t)c * HWc + rem];
        }

        // ---- density(x; mu, 1/rinv) ----
        float alpha[Kk], rho[Kk];
#pragma unroll
        for (int k = 0; k < Kk; k++) {
            float inv_s2 = rinv[k] * rinv[k];
            float d0 = x[0] - mu[k * Cc + 0];
            float d1 = x[1] - mu[k * Cc + 1];
            float d2 = x[2] - mu[k * Cc + 2];
            float dist = fmaf(d0, d0, fmaf(d1, d1, d2 * d2));
            float coef = C0 * inv_s2 * rinv[k];            // C0 * rinv^3
            float dens = coef * ex2(NH_L2E * dist * inv_s2);
            alpha[k] = pi[k] * dens;
            rho[k] = alpha[k] * dens;
        }

        // ---- pi MLP (10 -> 5 -> 5) + softmax over K ----
        float piN[Kk];
        {
            float h[Kk];
#pragma unroll
            for (int j = 0; j < Kk; j++) {
                float a = W[OPB1 + j];
#pragma unroll
                for (int i = 0; i < Kk; i++) a = fmaf(W[OPW1 + j * 2 * Kk + i], pi[i], a);
#pragma unroll
                for (int i = 0; i < Kk; i++) a = fmaf(W[OPW1 + j * 2 * Kk + Kk + i], alpha[i], a);
                h[j] = frelu(a);
            }
            float o[Kk];
            float m = -1e30f;
#pragma unroll
            for (int j = 0; j < Kk; j++) {
                float a = W[OPB2 + j];
#pragma unroll
                for (int i = 0; i < Kk; i++) a = fmaf(W[OPW2 + j * Kk + i], h[i], a);
                o[j] = a; m = fmaxf(m, a);
            }
            float sum = 0.0f;
#pragma unroll
            for (int j = 0; j < Kk; j++) { o[j] = ex2(LOG2E * (o[j] - m)); sum += o[j]; }
            float r = rcpf(sum);
#pragma unroll
            for (int j = 0; j < Kk; j++) piN[j] = o[j] * r;
        }

        // ---- mu MLP (23 -> 15 -> 15), sigmoid ----
        float muN[CKc];
        {
            float h[CKc];
#pragma unroll
            for (int j = 0; j < CKc; j++) {
                float a = W[OMB1 + j];
#pragma unroll
                for (int i = 0; i < Cc; i++)  a = fmaf(W[OMW1 + j * 23 + i], x[i], a);
#pragma unroll
                for (int i = 0; i < CKc; i++) a = fmaf(W[OMW1 + j * 23 + 3 + i], mu[i], a);
#pragma unroll
                for (int i = 0; i < Kk; i++)  a = fmaf(W[OMW1 + j * 23 + 18 + i], rho[i], a);
                h[j] = frelu(a);
            }
#pragma unroll
            for (int j = 0; j < CKc; j++) {
                float a = W[OMB2 + j];
#pragma unroll
                for (int i = 0; i < CKc; i++) a = fmaf(W[OMW2 + j * CKc + i], h[i], a);
                muN[j] = fsigm(a);
            }
        }

        // ---- sigma MLP (23 -> 5 -> 5): rinvN = exp(-relu(a)) = 1/sigma_new ----
        float rinvN[Kk];
        {
            float h[Kk];
#pragma unroll
            for (int j = 0; j < Kk; j++) {
                float a = W[OSB1 + j];
#pragma unroll
                for (int i = 0; i < Cc; i++)  a = fmaf(W[OSW1 + j * 23 + i], x[i], a);
#pragma unroll
                for (int i = 0; i < CKc; i++) a = fmaf(W[OSW1 + j * 23 + 3 + i], muN[i], a);
#pragma unroll
                for (int i = 0; i < Kk; i++)  a = fmaf(W[OSW1 + j * 23 + 18 + i], rho[i], a);
                h[j] = frelu(a);
            }
#pragma unroll
            for (int j = 0; j < Kk; j++) {
                float a = W[OSB2 + j];
#pragma unroll
                for (int i = 0; i < Kk; i++) a = fmaf(W[OSW2 + j * Kk + i], h[i], a);
                rinvN[j] = ex2(-LOG2E * frelu(a));
            }
        }

        // ---- dens2(x; muN, 1/rinvN), gamma MLP (5 -> 5 -> 1), sigmoid ----
        float gin[Kk];
#pragma unroll
        for (int k = 0; k < Kk; k++) {
            float inv_s2 = rinvN[k] * rinvN[k];
            float d0 = x[0] - muN[k * Cc + 0];
            float d1 = x[1] - muN[k * Cc + 1];
            float d2 = x[2] - muN[k * Cc + 2];
            float dist = fmaf(d0, d0, fmaf(d1, d1, d2 * d2));
            float coef = C0 * inv_s2 * rinvN[k];
            gin[k] = piN[k] * (coef * ex2(NH_L2E * dist * inv_s2));
        }
        {
            float h[Kk];
#pragma unroll
            for (int j = 0; j < Kk; j++) {
                float a = W[OGB1 + j];
#pragma unroll
                for (int i = 0; i < Kk; i++) a = fmaf(W[OGW1 + j * Kk + i], gin[i], a);
                h[j] = frelu(a);
            }
            float go = W[OGB2];
#pragma unroll
            for (int i = 0; i < Kk; i++) go = fmaf(W[OGW2 + i], h[i], go);
            out[(size_t)(b * Ss + s) * HWc + rem] = fsigm(go);
        }

        // ---- carry state ----
#pragma unroll
        for (int k = 0; k < Kk; k++) { pi[k] = piN[k]; rinv[k] = rinvN[k]; }
#pragma unroll
        for (int j = 0; j < CKc; j++) mu[j] = muN[j];
#pragma unroll
        for (int c = 0; c < Cc; c++) x[c] = xn[c];
    }
}

} // namespace

extern "C" void kernel_launch(void* const* d_in, const int* in_sizes, int n_in,
                              void* d_out, int out_size, void* d_ws, size_t ws_size,
                              hipStream_t stream) {
    const float* frames = (const float*)d_in[0];
    const float* mu0    = (const float*)d_in[2];
    const float* pw1 = (const float*)d_in[3];
    const float* pb1 = (const float*)d_in[4];
    const float* pw2 = (const float*)d_in[5];
    const float* pb2 = (const float*)d_in[6];
    const float* mw1 = (const float*)d_in[7];
    const float* mb1 = (const float*)d_in[8];
    const float* mw2 = (const float*)d_in[9];
    const float* mb2 = (const float*)d_in[10];
    const float* sw1 = (const float*)d_in[11];
    const float* sb1 = (const float*)d_in[12];
    const float* sw2 = (const float*)d_in[13];
    const float* sb2 = (const float*)d_in[14];
    const float* gw1 = (const float*)d_in[15];
    const float* gb1 = (const float*)d_in[16];
    const float* gw2 = (const float*)d_in[17];
    const float* gb2 = (const float*)d_in[18];
    float* out = (float*)d_out;
    float* ws  = (float*)d_ws;

    // Stage all weights contiguous in d_ws (consumption order).
    stage_ws_kernel<<<1, 256, 0, stream>>>(
        pw1, pb1, pw2, pb2, mw1, mb1, mw2, mb2,
        sw1, sb1, sw2, sb2, gw1, gb1, gw2, gb2, ws);

    const int total = Bb * HWc;                      // 589,824 pixels
    const int grid = (total + BLOCK - 1) / BLOCK;    // 2304 blocks of 256

    gmm_seq_kernel<<<grid, BLOCK, 0, stream>>>(frames, mu0, ws, out);
}

// Round 5
// 276.462 us; speedup vs baseline: 1.0941x; 1.0941x over previous
//
#include <hip/hip_runtime.h>

// GMMNet: B=4,S=8,C=3,H=W=384,K=5. Pointwise per pixel; scan over S carries
// per-pixel state (pi[5], mu[15], rinv[5]=1/sigma) in registers.
//
// Round 13: RESUBMIT of R12 (container infra failure, kernel never ran).
//
// R12 theory: 2px/thread v2f (packed v_pk_fma_f32) + IN-PLACE state update.
// R10/R11 decomposition: v2f packs (87us VALU work vs 154us scalar) but
// R8's structure peaked ~224 VGPRs -> 2 waves/SIMD -> 65% busy -> 134us.
// Scalar got 96% busy at 50% occupancy but 2x work -> 160us. This round
// keeps packed math AND compresses liveness for 4 waves/SIMD:
//   rinv dead after density      -> rinvN written into rinv[]
//   pi,alpha dead after piMLP L1 -> piN written into pi[]
//   mu dead after muMLP L1       -> muN written into mu[]  (L2 reads only h)
//   rho dead after sigmaMLP L1
// Removes piN/muN/rinvN arrays entirely; peak live = state(62) + h(30)
// + temps ~= 110 VGPRs < 128. __launch_bounds__(256,4) -> 4 waves/SIMD.
// Predict: VGPR<=32 units, occupancy ~50%, VALUBusy ~90%, dispatch ~95us.
// Tripwire: VGPR>40 units => liveness compression failed => sched_barrier
// phase pinning or neuron-pair packing next.
//
// Retained: ONE contiguous d_ws weight buffer (staging kernel), consumption
// order, opaque per-step scalar offset (blocks weight-value hoisting into
// VGPRs - R2's 188-VGPR lesson), xn prefetch (6 regs, hides frame load).

namespace {

constexpr int Kk = 5;
constexpr int Cc = 3;
constexpr int CKc = 15;   // C*K
constexpr int Bb = 4;
constexpr int Ss = 8;
constexpr int HWc = 384 * 384;
constexpr int HW2 = HWc / 2;          // pixel-pairs per image
constexpr int BLOCK = 256;

// Contiguous weight layout (float offsets), consumption order.
constexpr int OPB1 = 0;     // pi_b1   5
constexpr int OPW1 = 5;     // pi_w1   5x10 = 50
constexpr int OPB2 = 55;    // pi_b2   5
constexpr int OPW2 = 60;    // pi_w2   5x5  = 25
constexpr int OMB1 = 85;    // mu_b1   15
constexpr int OMW1 = 100;   // mu_w1   15x23 = 345
constexpr int OMB2 = 445;   // mu_b2   15
constexpr int OMW2 = 460;   // mu_w2   15x15 = 225
constexpr int OSB1 = 685;   // sg_b1   5
constexpr int OSW1 = 690;   // sg_w1   5x23 = 115
constexpr int OSB2 = 805;   // sg_b2   5
constexpr int OSW2 = 810;   // sg_w2   5x5  = 25
constexpr int OGB1 = 835;   // ga_b1   5
constexpr int OGW1 = 840;   // ga_w1   5x5  = 25
constexpr int OGW2 = 865;   // ga_w2   5
constexpr int OGB2 = 870;   // ga_b2   1
constexpr int WTOT = 871;   // 3484 B

typedef float v2f __attribute__((ext_vector_type(2)));

__device__ __forceinline__ float rcpf(float x) { return __builtin_amdgcn_rcpf(x); }
__device__ __forceinline__ float ex2(float x) { return __builtin_amdgcn_exp2f(x); }

__device__ __forceinline__ v2f vsplat(float w) { v2f r = {w, w}; return r; }
__device__ __forceinline__ v2f vfma(v2f a, v2f b, v2f c) { return __builtin_elementwise_fma(a, b, c); }
__device__ __forceinline__ v2f wfma(float w, v2f x, v2f c) { return vfma(vsplat(w), x, c); }
__device__ __forceinline__ v2f vexp2(v2f v) { v2f r; r.x = ex2(v.x); r.y = ex2(v.y); return r; }
__device__ __forceinline__ v2f vrcp(v2f v) { v2f r; r.x = rcpf(v.x); r.y = rcpf(v.y); return r; }
__device__ __forceinline__ v2f vmax(v2f a, v2f b) { return __builtin_elementwise_max(a, b); }
__device__ __forceinline__ v2f vrelu(v2f a) { return vmax(a, vsplat(0.0f)); }
constexpr float LOG2E = 1.4426950408889634f;
__device__ __forceinline__ v2f vsigm(v2f a) { return vrcp(vsplat(1.0f) + vexp2(vsplat(-LOG2E) * a)); }

__global__ __launch_bounds__(256) void stage_ws_kernel(
    const float* __restrict__ pw1, const float* __restrict__ pb1,
    const float* __restrict__ pw2, const float* __restrict__ pb2,
    const float* __restrict__ mw1, const float* __restrict__ mb1,
    const float* __restrict__ mw2, const float* __restrict__ mb2,
    const float* __restrict__ sw1, const float* __restrict__ sb1,
    const float* __restrict__ sw2, const float* __restrict__ sb2,
    const float* __restrict__ gw1, const float* __restrict__ gb1,
    const float* __restrict__ gw2, const float* __restrict__ gb2,
    float* __restrict__ ws)
{
    const int t = threadIdx.x;
    auto cp = [&](const float* src, int off, int n) {
        for (int i = t; i < n; i += 256) ws[off + i] = src[i];
    };
    cp(pb1, OPB1, 5);   cp(pw1, OPW1, 50);
    cp(pb2, OPB2, 5);   cp(pw2, OPW2, 25);
    cp(mb1, OMB1, 15);  cp(mw1, OMW1, 345);
    cp(mb2, OMB2, 15);  cp(mw2, OMW2, 225);
    cp(sb1, OSB1, 5);   cp(sw1, OSW1, 115);
    cp(sb2, OSB2, 5);   cp(sw2, OSW2, 25);
    cp(gb1, OGB1, 5);   cp(gw1, OGW1, 25);
    cp(gw2, OGW2, 5);   cp(gb2, OGB2, 1);
}

__global__ __launch_bounds__(BLOCK, 4) void gmm_seq_kernel(
    const float* __restrict__ frames,
    const float* __restrict__ mu0,
    const float* __restrict__ Wt,     // contiguous weights in d_ws
    float* __restrict__ out)
{
    const int t2 = blockIdx.x * BLOCK + threadIdx.x;   // one thread = 2 adjacent px
    const int b   = t2 / HW2;
    const int rem = t2 - b * HW2;

    const float C0 = 0.06349363593424097f;      // (2*pi)^{-3/2}
    const float NH_L2E = -0.7213475204444817f;  // -0.5 * log2(e)

    // Per-pixel-pair carried state, updated IN PLACE each step.
    v2f pi[Kk], mu[CKc], rinv[Kk];              // rinv = 1/sigma
#pragma unroll
    for (int k = 0; k < Kk; k++) { pi[k] = vsplat(0.2f); rinv[k] = vsplat(1.0f); }
    {
        const float* mp = mu0 + (size_t)b * CKc * HWc;
#pragma unroll
        for (int j = 0; j < CKc; j++)
            mu[j] = reinterpret_cast<const v2f*>(mp + (size_t)j * HWc)[rem];
    }

    const float* fbase = frames + ((size_t)b * Ss * Cc) * HWc;
    v2f x[Cc];
#pragma unroll
    for (int c = 0; c < Cc; c++)
        x[c] = reinterpret_cast<const v2f*>(fbase + (size_t)c * HWc)[rem];

#pragma unroll 1
    for (int s = 0; s < Ss; s++) {
        // Opaque per-iteration SCALAR offset: value is always 0 but unprovable.
        // Addresses stay wave-uniform (s_load path), loads stay loop-variant
        // (no cross-step hoisting of weight VALUES into registers).
        long woff = 0;
        asm volatile("" : "+s"(woff));
        const float* W = Wt + woff;

        // Prefetch next frame's pixels (clamped index -> branchless).
        const int sn = (s + 1 < Ss) ? s + 1 : s;
        v2f xn[Cc];
        {
            const float* fp = fbase + ((size_t)sn * Cc) * HWc;
#pragma unroll
            for (int c = 0; c < Cc; c++)
                xn[c] = reinterpret_cast<const v2f*>(fp + (size_t)c * HWc)[rem];
        }

        // ---- density(x; mu, 1/rinv) ----  (rinv DEAD after this phase)
        v2f alpha[Kk], rho[Kk];
#pragma unroll
        for (int k = 0; k < Kk; k++) {
            v2f inv_s2 = rinv[k] * rinv[k];
            v2f d0 = x[0] - mu[k * Cc + 0];
            v2f d1 = x[1] - mu[k * Cc + 1];
            v2f d2 = x[2] - mu[k * Cc + 2];
            v2f dist = vfma(d0, d0, vfma(d1, d1, d2 * d2));
            v2f coef = vsplat(C0) * inv_s2 * rinv[k];      // C0 * rinv^3
            v2f dens = coef * vexp2(vsplat(NH_L2E) * dist * inv_s2);
            alpha[k] = pi[k] * dens;
            rho[k] = alpha[k] * dens;
        }

        // ---- pi MLP (10 -> 5 -> 5) + softmax; result IN PLACE into pi[] ----
        {
            v2f h[Kk];
#pragma unroll
            for (int j = 0; j < Kk; j++) {
                v2f a = vsplat(W[OPB1 + j]);
#pragma unroll
                for (int i = 0; i < Kk; i++) a = wfma(W[OPW1 + j * 2 * Kk + i], pi[i], a);
#pragma unroll
                for (int i = 0; i < Kk; i++) a = wfma(W[OPW1 + j * 2 * Kk + Kk + i], alpha[i], a);
                h[j] = vrelu(a);
            }
            // pi[] and alpha[] dead now.
            v2f o[Kk];
            v2f m = vsplat(-1e30f);
#pragma unroll
            for (int j = 0; j < Kk; j++) {
                v2f a = vsplat(W[OPB2 + j]);
#pragma unroll
                for (int i = 0; i < Kk; i++) a = wfma(W[OPW2 + j * Kk + i], h[i], a);
                o[j] = a; m = vmax(m, a);
            }
            v2f sum = vsplat(0.0f);
#pragma unroll
            for (int j = 0; j < Kk; j++) { o[j] = vexp2(vsplat(LOG2E) * (o[j] - m)); sum = sum + o[j]; }
            v2f r = vrcp(sum);
#pragma unroll
            for (int j = 0; j < Kk; j++) pi[j] = o[j] * r;   // pi := pi_new
        }

        // ---- mu MLP (23 -> 15 -> 15), sigmoid; result IN PLACE into mu[] ----
        {
            v2f h[CKc];
#pragma unroll
            for (int j = 0; j < CKc; j++) {
                v2f a = vsplat(W[OMB1 + j]);
#pragma unroll
                for (int i = 0; i < Cc; i++)  a = wfma(W[OMW1 + j * 23 + i], x[i], a);
#pragma unroll
                for (int i = 0; i < CKc; i++) a = wfma(W[OMW1 + j * 23 + 3 + i], mu[i], a);
#pragma unroll
                for (int i = 0; i < Kk; i++)  a = wfma(W[OMW1 + j * 23 + 18 + i], rho[i], a);
                h[j] = vrelu(a);
            }
            // mu[] dead now; L2 reads only h[].
#pragma unroll
            for (int j = 0; j < CKc; j++) {
                v2f a = vsplat(W[OMB2 + j]);
#pragma unroll
                for (int i = 0; i < CKc; i++) a = wfma(W[OMW2 + j * CKc + i], h[i], a);
                mu[j] = vsigm(a);                            // mu := mu_new
            }
        }

        // ---- sigma MLP (23 -> 5 -> 5); rinv := exp(-relu(a)) IN PLACE ----
        {
            v2f h[Kk];
#pragma unroll
            for (int j = 0; j < Kk; j++) {
                v2f a = vsplat(W[OSB1 + j]);
#pragma unroll
                for (int i = 0; i < Cc; i++)  a = wfma(W[OSW1 + j * 23 + i], x[i], a);
#pragma unroll
                for (int i = 0; i < CKc; i++) a = wfma(W[OSW1 + j * 23 + 3 + i], mu[i], a);
#pragma unroll
                for (int i = 0; i < Kk; i++)  a = wfma(W[OSW1 + j * 23 + 18 + i], rho[i], a);
                h[j] = vrelu(a);
            }
            // rho[] dead now.
#pragma unroll
            for (int j = 0; j < Kk; j++) {
                v2f a = vsplat(W[OSB2 + j]);
#pragma unroll
                for (int i = 0; i < Kk; i++) a = wfma(W[OSW2 + j * Kk + i], h[i], a);
                rinv[j] = vexp2(vsplat(-LOG2E) * vrelu(a));  // rinv := 1/sigma_new
            }
        }

        // ---- dens2(x; mu_new, rinv_new), gamma MLP (5 -> 5 -> 1), sigmoid ----
        v2f gin[Kk];
#pragma unroll
        for (int k = 0; k < Kk; k++) {
            v2f inv_s2 = rinv[k] * rinv[k];
            v2f d0 = x[0] - mu[k * Cc + 0];
            v2f d1 = x[1] - mu[k * Cc + 1];
            v2f d2 = x[2] - mu[k * Cc + 2];
            v2f dist = vfma(d0, d0, vfma(d1, d1, d2 * d2));
            v2f coef = vsplat(C0) * inv_s2 * rinv[k];
            gin[k] = pi[k] * (coef * vexp2(vsplat(NH_L2E) * dist * inv_s2));
        }
        {
            v2f h[Kk];
#pragma unroll
            for (int j = 0; j < Kk; j++) {
                v2f a = vsplat(W[OGB1 + j]);
#pragma unroll
                for (int i = 0; i < Kk; i++) a = wfma(W[OGW1 + j * Kk + i], gin[i], a);
                h[j] = vrelu(a);
            }
            v2f go = vsplat(W[OGB2]);
#pragma unroll
            for (int i = 0; i < Kk; i++) go = wfma(W[OGW2 + i], h[i], go);
            reinterpret_cast<v2f*>(out + (size_t)(b * Ss + s) * HWc)[rem] = vsigm(go);
        }

        // ---- advance frame ----
#pragma unroll
        for (int c = 0; c < Cc; c++) x[c] = xn[c];
    }
}

} // namespace

extern "C" void kernel_launch(void* const* d_in, const int* in_sizes, int n_in,
                              void* d_out, int out_size, void* d_ws, size_t ws_size,
                              hipStream_t stream) {
    const float* frames = (const float*)d_in[0];
    const float* mu0    = (const float*)d_in[2];
    const float* pw1 = (const float*)d_in[3];
    const float* pb1 = (const float*)d_in[4];
    const float* pw2 = (const float*)d_in[5];
    const float* pb2 = (const float*)d_in[6];
    const float* mw1 = (const float*)d_in[7];
    const float* mb1 = (const float*)d_in[8];
    const float* mw2 = (const float*)d_in[9];
    const float* mb2 = (const float*)d_in[10];
    const float* sw1 = (const float*)d_in[11];
    const float* sb1 = (const float*)d_in[12];
    const float* sw2 = (const float*)d_in[13];
    const float* sb2 = (const float*)d_in[14];
    const float* gw1 = (const float*)d_in[15];
    const float* gb1 = (const float*)d_in[16];
    const float* gw2 = (const float*)d_in[17];
    const float* gb2 = (const float*)d_in[18];
    float* out = (float*)d_out;
    float* ws  = (float*)d_ws;

    // Stage all weights contiguous in d_ws (consumption order).
    stage_ws_kernel<<<1, 256, 0, stream>>>(
        pw1, pb1, pw2, pb2, mw1, mb1, mw2, mb2,
        sw1, sb1, sw2, sb2, gw1, gb1, gw2, gb2, ws);

    const int total2 = Bb * HW2;                     // 294,912 pixel-pairs
    const int grid = (total2 + BLOCK - 1) / BLOCK;   // 1152 blocks of 256

    gmm_seq_kernel<<<grid, BLOCK, 0, stream>>>(frames, mu0, ws, out);
}

// Round 6
// 275.562 us; speedup vs baseline: 1.0977x; 1.0033x over previous
//
#include <hip/hip_runtime.h>

// GMMNet: B=4,S=8,C=3,H=W=384,K=5. Pointwise per pixel; scan over S carries
// per-pixel state (pi[5], mu[15], rinv[5]=1/sigma) in registers.
//
// Round 14: HARD VGPR CLAMP via __attribute__((amdgpu_num_vgpr(128))).
// R13 post-mortem: in-place state update was a semantic NO-OP (SSA renames
// arrays away; pressure is dataflow+schedule, not naming) -- counters were
// byte-identical to R8/R10 (56 units=224 VGPRs, 32% occ, 57% busy, 149us).
// Three rounds prove __launch_bounds__ min-waves is IGNORED by the RA for
// this kernel (hint, not constraint). amdgpu_num_vgpr is the hard budget:
// RA must schedule-for-pressure (or spill) to honor it. Genuine peak
// liveness is ~92-110 regs (state 62 + h 30 + temps), so 128 is feasible
// with little/no spill. Packed v2f work is ~87us (R8/R13: busy*dur); at
// 4 waves/SIMD R11 showed 96% busy on this access pattern.
// Predict: VGPR 56->32 units, occ ~50%, busy ~90%, dispatch ~95-105us.
// Tripwires: VGPR stays 56 => attribute ignored too -> restructure
// (two-kernel split / LDS state). WRITE_SIZE jump => spilling -> relax
// to num_vgpr(160) (3 waves/SIMD).
//
// Retained: 2px/thread v2f packed math, ONE contiguous d_ws weight buffer
// (staging kernel, consumption order), opaque per-step scalar offset
// (blocks weight-value hoisting into VGPRs - R2's 188-VGPR lesson),
// xn prefetch (6 regs; overlaps whole body).

namespace {

constexpr int Kk = 5;
constexpr int Cc = 3;
constexpr int CKc = 15;   // C*K
constexpr int Bb = 4;
constexpr int Ss = 8;
constexpr int HWc = 384 * 384;
constexpr int HW2 = HWc / 2;          // pixel-pairs per image
constexpr int BLOCK = 256;

// Contiguous weight layout (float offsets), consumption order.
constexpr int OPB1 = 0;     // pi_b1   5
constexpr int OPW1 = 5;     // pi_w1   5x10 = 50
constexpr int OPB2 = 55;    // pi_b2   5
constexpr int OPW2 = 60;    // pi_w2   5x5  = 25
constexpr int OMB1 = 85;    // mu_b1   15
constexpr int OMW1 = 100;   // mu_w1   15x23 = 345
constexpr int OMB2 = 445;   // mu_b2   15
constexpr int OMW2 = 460;   // mu_w2   15x15 = 225
constexpr int OSB1 = 685;   // sg_b1   5
constexpr int OSW1 = 690;   // sg_w1   5x23 = 115
constexpr int OSB2 = 805;   // sg_b2   5
constexpr int OSW2 = 810;   // sg_w2   5x5  = 25
constexpr int OGB1 = 835;   // ga_b1   5
constexpr int OGW1 = 840;   // ga_w1   5x5  = 25
constexpr int OGW2 = 865;   // ga_w2   5
constexpr int OGB2 = 870;   // ga_b2   1
constexpr int WTOT = 871;   // 3484 B

typedef float v2f __attribute__((ext_vector_type(2)));

__device__ __forceinline__ float rcpf(float x) { return __builtin_amdgcn_rcpf(x); }
__device__ __forceinline__ float ex2(float x) { return __builtin_amdgcn_exp2f(x); }

__device__ __forceinline__ v2f vsplat(float w) { v2f r = {w, w}; return r; }
__device__ __forceinline__ v2f vfma(v2f a, v2f b, v2f c) { return __builtin_elementwise_fma(a, b, c); }
__device__ __forceinline__ v2f wfma(float w, v2f x, v2f c) { return vfma(vsplat(w), x, c); }
__device__ __forceinline__ v2f vexp2(v2f v) { v2f r; r.x = ex2(v.x); r.y = ex2(v.y); return r; }
__device__ __forceinline__ v2f vrcp(v2f v) { v2f r; r.x = rcpf(v.x); r.y = rcpf(v.y); return r; }
__device__ __forceinline__ v2f vmax(v2f a, v2f b) { return __builtin_elementwise_max(a, b); }
__device__ __forceinline__ v2f vrelu(v2f a) { return vmax(a, vsplat(0.0f)); }
constexpr float LOG2E = 1.4426950408889634f;
__device__ __forceinline__ v2f vsigm(v2f a) { return vrcp(vsplat(1.0f) + vexp2(vsplat(-LOG2E) * a)); }

__global__ __launch_bounds__(256) void stage_ws_kernel(
    const float* __restrict__ pw1, const float* __restrict__ pb1,
    const float* __restrict__ pw2, const float* __restrict__ pb2,
    const float* __restrict__ mw1, const float* __restrict__ mb1,
    const float* __restrict__ mw2, const float* __restrict__ mb2,
    const float* __restrict__ sw1, const float* __restrict__ sb1,
    const float* __restrict__ sw2, const float* __restrict__ sb2,
    const float* __restrict__ gw1, const float* __restrict__ gb1,
    const float* __restrict__ gw2, const float* __restrict__ gb2,
    float* __restrict__ ws)
{
    const int t = threadIdx.x;
    auto cp = [&](const float* src, int off, int n) {
        for (int i = t; i < n; i += 256) ws[off + i] = src[i];
    };
    cp(pb1, OPB1, 5);   cp(pw1, OPW1, 50);
    cp(pb2, OPB2, 5);   cp(pw2, OPW2, 25);
    cp(mb1, OMB1, 15);  cp(mw1, OMW1, 345);
    cp(mb2, OMB2, 15);  cp(mw2, OMW2, 225);
    cp(sb1, OSB1, 5);   cp(sw1, OSW1, 115);
    cp(sb2, OSB2, 5);   cp(sw2, OSW2, 25);
    cp(gb1, OGB1, 5);   cp(gw1, OGW1, 25);
    cp(gw2, OGW2, 5);   cp(gb2, OGB2, 1);
}

__global__ __attribute__((amdgpu_num_vgpr(128))) __launch_bounds__(BLOCK, 4)
void gmm_seq_kernel(
    const float* __restrict__ frames,
    const float* __restrict__ mu0,
    const float* __restrict__ Wt,     // contiguous weights in d_ws
    float* __restrict__ out)
{
    const int t2 = blockIdx.x * BLOCK + threadIdx.x;   // one thread = 2 adjacent px
    const int b   = t2 / HW2;
    const int rem = t2 - b * HW2;

    const float C0 = 0.06349363593424097f;      // (2*pi)^{-3/2}
    const float NH_L2E = -0.7213475204444817f;  // -0.5 * log2(e)

    // Per-pixel-pair carried state, updated in place each step.
    v2f pi[Kk], mu[CKc], rinv[Kk];              // rinv = 1/sigma
#pragma unroll
    for (int k = 0; k < Kk; k++) { pi[k] = vsplat(0.2f); rinv[k] = vsplat(1.0f); }
    {
        const float* mp = mu0 + (size_t)b * CKc * HWc;
#pragma unroll
        for (int j = 0; j < CKc; j++)
            mu[j] = reinterpret_cast<const v2f*>(mp + (size_t)j * HWc)[rem];
    }

    const float* fbase = frames + ((size_t)b * Ss * Cc) * HWc;
    v2f x[Cc];
#pragma unroll
    for (int c = 0; c < Cc; c++)
        x[c] = reinterpret_cast<const v2f*>(fbase + (size_t)c * HWc)[rem];

#pragma unroll 1
    for (int s = 0; s < Ss; s++) {
        // Opaque per-iteration SCALAR offset: value is always 0 but unprovable.
        // Addresses stay wave-uniform (s_load path), loads stay loop-variant
        // (no cross-step hoisting of weight VALUES into registers).
        long woff = 0;
        asm volatile("" : "+s"(woff));
        const float* W = Wt + woff;

        // Prefetch next frame's pixels (clamped index -> branchless).
        const int sn = (s + 1 < Ss) ? s + 1 : s;
        v2f xn[Cc];
        {
            const float* fp = fbase + ((size_t)sn * Cc) * HWc;
#pragma unroll
            for (int c = 0; c < Cc; c++)
                xn[c] = reinterpret_cast<const v2f*>(fp + (size_t)c * HWc)[rem];
        }

        // ---- density(x; mu, 1/rinv) ----  (rinv DEAD after this phase)
        v2f alpha[Kk], rho[Kk];
#pragma unroll
        for (int k = 0; k < Kk; k++) {
            v2f inv_s2 = rinv[k] * rinv[k];
            v2f d0 = x[0] - mu[k * Cc + 0];
            v2f d1 = x[1] - mu[k * Cc + 1];
            v2f d2 = x[2] - mu[k * Cc + 2];
            v2f dist = vfma(d0, d0, vfma(d1, d1, d2 * d2));
            v2f coef = vsplat(C0) * inv_s2 * rinv[k];      // C0 * rinv^3
            v2f dens = coef * vexp2(vsplat(NH_L2E) * dist * inv_s2);
            alpha[k] = pi[k] * dens;
            rho[k] = alpha[k] * dens;
        }

        // ---- pi MLP (10 -> 5 -> 5) + softmax; result into pi[] ----
        {
            v2f h[Kk];
#pragma unroll
            for (int j = 0; j < Kk; j++) {
                v2f a = vsplat(W[OPB1 + j]);
#pragma unroll
                for (int i = 0; i < Kk; i++) a = wfma(W[OPW1 + j * 2 * Kk + i], pi[i], a);
#pragma unroll
                for (int i = 0; i < Kk; i++) a = wfma(W[OPW1 + j * 2 * Kk + Kk + i], alpha[i], a);
                h[j] = vrelu(a);
            }
            // pi[] and alpha[] dead now.
            v2f o[Kk];
            v2f m = vsplat(-1e30f);
#pragma unroll
            for (int j = 0; j < Kk; j++) {
                v2f a = vsplat(W[OPB2 + j]);
#pragma unroll
                for (int i = 0; i < Kk; i++) a = wfma(W[OPW2 + j * Kk + i], h[i], a);
                o[j] = a; m = vmax(m, a);
            }
            v2f sum = vsplat(0.0f);
#pragma unroll
            for (int j = 0; j < Kk; j++) { o[j] = vexp2(vsplat(LOG2E) * (o[j] - m)); sum = sum + o[j]; }
            v2f r = vrcp(sum);
#pragma unroll
            for (int j = 0; j < Kk; j++) pi[j] = o[j] * r;   // pi := pi_new
        }

        // ---- mu MLP (23 -> 15 -> 15), sigmoid; result into mu[] ----
        {
            v2f h[CKc];
#pragma unroll
            for (int j = 0; j < CKc; j++) {
                v2f a = vsplat(W[OMB1 + j]);
#pragma unroll
                for (int i = 0; i < Cc; i++)  a = wfma(W[OMW1 + j * 23 + i], x[i], a);
#pragma unroll
                for (int i = 0; i < CKc; i++) a = wfma(W[OMW1 + j * 23 + 3 + i], mu[i], a);
#pragma unroll
                for (int i = 0; i < Kk; i++)  a = wfma(W[OMW1 + j * 23 + 18 + i], rho[i], a);
                h[j] = vrelu(a);
            }
            // mu[] dead now; L2 reads only h[].
#pragma unroll
            for (int j = 0; j < CKc; j++) {
                v2f a = vsplat(W[OMB2 + j]);
#pragma unroll
                for (int i = 0; i < CKc; i++) a = wfma(W[OMW2 + j * CKc + i], h[i], a);
                mu[j] = vsigm(a);                            // mu := mu_new
            }
        }

        // ---- sigma MLP (23 -> 5 -> 5); rinv := exp(-relu(a)) ----
        {
            v2f h[Kk];
#pragma unroll
            for (int j = 0; j < Kk; j++) {
                v2f a = vsplat(W[OSB1 + j]);
#pragma unroll
                for (int i = 0; i < Cc; i++)  a = wfma(W[OSW1 + j * 23 + i], x[i], a);
#pragma unroll
                for (int i = 0; i < CKc; i++) a = wfma(W[OSW1 + j * 23 + 3 + i], mu[i], a);
#pragma unroll
                for (int i = 0; i < Kk; i++)  a = wfma(W[OSW1 + j * 23 + 18 + i], rho[i], a);
                h[j] = vrelu(a);
            }
            // rho[] dead now.
#pragma unroll
            for (int j = 0; j < Kk; j++) {
                v2f a = vsplat(W[OSB2 + j]);
#pragma unroll
                for (int i = 0; i < Kk; i++) a = wfma(W[OSW2 + j * Kk + i], h[i], a);
                rinv[j] = vexp2(vsplat(-LOG2E) * vrelu(a));  // rinv := 1/sigma_new
            }
        }

        // ---- dens2(x; mu_new, rinv_new), gamma MLP (5 -> 5 -> 1), sigmoid ----
        v2f gin[Kk];
#pragma unroll
        for (int k = 0; k < Kk; k++) {
            v2f inv_s2 = rinv[k] * rinv[k];
            v2f d0 = x[0] - mu[k * Cc + 0];
            v2f d1 = x[1] - mu[k * Cc + 1];
            v2f d2 = x[2] - mu[k * Cc + 2];
            v2f dist = vfma(d0, d0, vfma(d1, d1, d2 * d2));
            v2f coef = vsplat(C0) * inv_s2 * rinv[k];
            gin[k] = pi[k] * (coef * vexp2(vsplat(NH_L2E) * dist * inv_s2));
        }
        {
            v2f h[Kk];
#pragma unroll
            for (int j = 0; j < Kk; j++) {
                v2f a = vsplat(W[OGB1 + j]);
#pragma unroll
                for (int i = 0; i < Kk; i++) a = wfma(W[OGW1 + j * Kk + i], gin[i], a);
                h[j] = vrelu(a);
            }
            v2f go = vsplat(W[OGB2]);
#pragma unroll
            for (int i = 0; i < Kk; i++) go = wfma(W[OGW2 + i], h[i], go);
            reinterpret_cast<v2f*>(out + (size_t)(b * Ss + s) * HWc)[rem] = vsigm(go);
        }

        // ---- advance frame ----
#pragma unroll
        for (int c = 0; c < Cc; c++) x[c] = xn[c];
    }
}

} // namespace

extern "C" void kernel_launch(void* const* d_in, const int* in_sizes, int n_in,
                              void* d_out, int out_size, void* d_ws, size_t ws_size,
                              hipStream_t stream) {
    const float* frames = (const float*)d_in[0];
    const float* mu0    = (const float*)d_in[2];
    const float* pw1 = (const float*)d_in[3];
    const float* pb1 = (const float*)d_in[4];
    const float* pw2 = (const float*)d_in[5];
    const float* pb2 = (const float*)d_in[6];
    const float* mw1 = (const float*)d_in[7];
    const float* mb1 = (const float*)d_in[8];
    const float* mw2 = (const float*)d_in[9];
    const float* mb2 = (const float*)d_in[10];
    const float* sw1 = (const float*)d_in[11];
    const float* sb1 = (const float*)d_in[12];
    const float* sw2 = (const float*)d_in[13];
    const float* sb2 = (const float*)d_in[14];
    const float* gw1 = (const float*)d_in[15];
    const float* gb1 = (const float*)d_in[16];
    const float* gw2 = (const float*)d_in[17];
    const float* gb2 = (const float*)d_in[18];
    float* out = (float*)d_out;
    float* ws  = (float*)d_ws;

    // Stage all weights contiguous in d_ws (consumption order).
    stage_ws_kernel<<<1, 256, 0, stream>>>(
        pw1, pb1, pw2, pb2, mw1, mb1, mw2, mb2,
        sw1, sb1, sw2, sb2, gw1, gb1, gw2, gb2, ws);

    const int total2 = Bb * HW2;                     // 294,912 pixel-pairs
    const int grid = (total2 + BLOCK - 1) / BLOCK;   // 1152 blocks of 256

    gmm_seq_kernel<<<grid, BLOCK, 0, stream>>>(frames, mu0, ws, out);
}